// Round 3
// baseline (326.838 us; speedup 1.0000x reference)
//
#include <hip/hip_runtime.h>
#include <hip/hip_bf16.h>

// ---- problem constants ----
#define NW 5
#define KS 5
#define SEQ 196
#define DIM 384
#define NSUP 25        // NW*KS support images
#define NQRY 75        // query images
#define NIMG 100       // NSUP + NQRY
#define LSUP 4900      // NSUP*SEQ support rows
#define LSUP_PAD 4992  // 39*128, zero-padded K rows
#define QROWS 208      // padded qs rows per image (13*16)
#define BLOCK_W 980    // KS*SEQ rows per class block
#define OPT_STEPS 15
#define MTILES 39      // LSUP_PAD / MT

static constexpr float TEMP_F = 0.0510310363f;
static constexpr float INV_T  = 1.0f / TEMP_F;   // ~19.5959
static constexpr float LR_F   = 0.1f;

typedef short v8s __attribute__((ext_vector_type(8)));   // 8 x bf16 frag (4 VGPRs)
typedef float v4f __attribute__((ext_vector_type(4)));   // 4 x f32 acc

__device__ inline unsigned short f2bf(float x) {
    unsigned int u = __float_as_uint(x);
    u += 0x7fffu + ((u >> 16) & 1u);
    return (unsigned short)(u >> 16);
}

// ---------------------------------------------------------------------------
// Kernel 1a: K-side normalize (pre-scaled by 1/T). Wave-per-row, no LDS/sync.
// ---------------------------------------------------------------------------
__global__ __launch_bounds__(256) void norm_k(const float* __restrict__ src,
                                              unsigned short* __restrict__ dst) {
    int row = blockIdx.x * 4 + (threadIdx.x >> 6);
    int l = threadIdx.x & 63;
    unsigned short* out = dst + (size_t)row * DIM;
    if (row >= LSUP) {
        #pragma unroll
        for (int k = 0; k < 6; ++k) out[l + 64 * k] = 0;
        return;
    }
    const float* in = src + (size_t)row * DIM;
    float x[6];
    #pragma unroll
    for (int k = 0; k < 6; ++k) x[k] = in[l + 64 * k];
    float s = 0.f;
    #pragma unroll
    for (int k = 0; k < 6; ++k) s += x[k] * x[k];
    #pragma unroll
    for (int m = 1; m < 64; m <<= 1) s += __shfl_xor(s, m);
    float sc = INV_T / fmaxf(sqrtf(s), 1e-8f);
    #pragma unroll
    for (int k = 0; k < 6; ++k) out[l + 64 * k] = f2bf(x[k] * sc);
}

// ---------------------------------------------------------------------------
// Kernel 1b: Q-side normalize into padded [100][208][384]. Wave-per-row.
// ---------------------------------------------------------------------------
__global__ __launch_bounds__(256) void norm_q(const float* __restrict__ supq,
                                              const float* __restrict__ qry,
                                              unsigned short* __restrict__ dst) {
    int r = blockIdx.x * 4 + (threadIdx.x >> 6);   // 0..207
    int img = blockIdx.y;                          // 0..99
    int l = threadIdx.x & 63;
    unsigned short* out = dst + ((size_t)img * QROWS + r) * DIM;
    if (r >= SEQ) {
        #pragma unroll
        for (int k = 0; k < 6; ++k) out[l + 64 * k] = 0;
        return;
    }
    const float* in = (img < NSUP)
        ? supq + ((size_t)img * SEQ + r) * DIM
        : qry  + ((size_t)(img - NSUP) * SEQ + r) * DIM;
    float x[6];
    #pragma unroll
    for (int k = 0; k < 6; ++k) x[k] = in[l + 64 * k];
    float s = 0.f;
    #pragma unroll
    for (int k = 0; k < 6; ++k) s += x[k] * x[k];
    #pragma unroll
    for (int m = 1; m < 64; m <<= 1) s += __shfl_xor(s, m);
    float sc = 1.0f / fmaxf(sqrtf(s), 1e-8f);
    #pragma unroll
    for (int k = 0; k < 6; ++k) out[l + 64 * k] = f2bf(x[k] * sc);
}

// ---------------------------------------------------------------------------
// Kernel 2: MFMA fused exp-sum GEMM, global_load_lds + XOR swizzle, XCD remap.
// 2M x 2N wave split: wave (wv>>1 = M-half, wv&1 = N-half) owns 64 rows x
// 7(6) col-tiles -> per kk: 4 A + 7 B ds_reads feed 28 MFMAs (was 15 for 26).
// ---------------------------------------------------------------------------
#define MT  128
#define NTP 208
#define NTT 13
#define KCC 64

__device__ __forceinline__ void gload16(const void* g, void* l) {
    __builtin_amdgcn_global_load_lds(
        (__attribute__((address_space(1))) void*)g,
        (__attribute__((address_space(3))) void*)l, 16, 0, 0);
}

__global__ __launch_bounds__(256, 3) void fused_expsum_mfma(
    const unsigned short* __restrict__ Kb,     // [4992][384] bf16, pre /T
    const unsigned short* __restrict__ Qall,   // [100][208][384] bf16
    float* __restrict__ Rall)
{
    __shared__ __align__(16) unsigned short Asm[MT * KCC];    // 16 KiB
    __shared__ __align__(16) unsigned short Bsm[NTP * KCC];   // 26 KiB

    int t = threadIdx.x;

    // bijective XCD-aware remap (m204): NWG=3900, q=487, r=4
    int bid = blockIdx.x;
    int xcd = bid & 7;
    int sub = bid >> 3;
    const int qq = (MTILES * NIMG) >> 3;   // 487
    const int rr = (MTILES * NIMG) & 7;    // 4
    int L = (xcd < rr ? xcd * (qq + 1) : rr * (qq + 1) + (xcd - rr) * qq) + sub;
    int img = L / MTILES;
    int m_base = (L - img * MTILES) * MT;

    const unsigned short* Qimg = Qall + (size_t)img * (QROWS * DIM);

    int wv = t >> 6;        // wave 0..3
    int l  = t & 63;
    int lo = l & 15;        // MFMA frag row/col index
    int hi = l >> 4;        // k-group
    int mh = (wv >> 1) * 64;   // M-half base row
    int nh = wv & 1;           // N-half (tiles nh*7 .., 7 or 6 tiles)

    // staging: each global_load_lds writes 1024B = 8 rows x 128B, linear.
    // lane l covers (row = l>>3, 16B slot = l&7); source k-slot pre-swizzled.
    int srow = l >> 3;
    int skp  = (l & 7) ^ srow;      // involution within 8-slot row
    const unsigned short* aSrc = Kb   + (size_t)(m_base + wv * 32 + srow) * DIM + skp * 8;
    const unsigned short* bSrc = Qimg + (size_t)srow * DIM + skp * 8;

    v4f acc[4][7];
    #pragma unroll
    for (int m = 0; m < 4; ++m)
        #pragma unroll
        for (int n = 0; n < 7; ++n)
            acc[m][n] = (v4f){0.f, 0.f, 0.f, 0.f};

    for (int kb = 0; kb < DIM; kb += KCC) {
        // A: wave wv stages rows [wv*32, wv*32+32) as 4 x 8-row groups
        #pragma unroll
        for (int j = 0; j < 4; ++j)
            gload16(aSrc + (size_t)j * 8 * DIM + kb,
                    Asm + (wv * 32 + j * 8) * KCC);
        // B: 26 8-row groups round-robined over 4 waves
        #pragma unroll
        for (int jj = 0; jj < 7; ++jj) {
            int j = wv + jj * 4;
            if (j < 26)
                gload16(bSrc + (size_t)j * 8 * DIM + kb,
                        Bsm + j * 8 * KCC);
        }
        __syncthreads();   // drains vmcnt before LDS reads

        const unsigned short* Ar = Asm + (mh + lo) * KCC;
        const unsigned short* Br = Bsm + (nh * 112 + lo) * KCC;
        #pragma unroll
        for (int kk = 0; kk < 2; ++kk) {
            int koff = ((hi + 4 * kk) ^ (lo & 7)) * 8;   // swizzled k-slot
            v8s a0 = *(const v8s*)(Ar + koff);
            v8s a1 = *(const v8s*)(Ar + 16 * KCC + koff);
            v8s a2 = *(const v8s*)(Ar + 32 * KCC + koff);
            v8s a3 = *(const v8s*)(Ar + 48 * KCC + koff);
            #pragma unroll
            for (int n = 0; n < 7; ++n) {
                if (nh == 0 || n < 6) {   // wave-uniform; skips tile 13
                    v8s bb = *(const v8s*)(Br + n * 16 * KCC + koff);
                    acc[0][n] = __builtin_amdgcn_mfma_f32_16x16x32_bf16(a0, bb, acc[0][n], 0, 0, 0);
                    acc[1][n] = __builtin_amdgcn_mfma_f32_16x16x32_bf16(a1, bb, acc[1][n], 0, 0, 0);
                    acc[2][n] = __builtin_amdgcn_mfma_f32_16x16x32_bf16(a2, bb, acc[2][n], 0, 0, 0);
                    acc[3][n] = __builtin_amdgcn_mfma_f32_16x16x32_bf16(a3, bb, acc[3][n], 0, 0, 0);
                }
            }
        }
        __syncthreads();
    }

    // epilogue: exp + per-wave column-half sums. C/D: col=lo, row=hi*4+reg.
    float s[4][4];   // [m][j]
    #pragma unroll
    for (int m = 0; m < 4; ++m)
        #pragma unroll
        for (int j = 0; j < 4; ++j) s[m][j] = 0.f;
    #pragma unroll
    for (int n = 0; n < 7; ++n) {
        if (nh == 0 || n < 6) {
            bool ok = ((nh * 7 + n) * 16 + lo) < SEQ;
            #pragma unroll
            for (int m = 0; m < 4; ++m)
                #pragma unroll
                for (int j = 0; j < 4; ++j)
                    s[m][j] += ok ? __expf(acc[m][n][j]) : 0.f;
        }
    }
    #pragma unroll
    for (int mm = 1; mm < 16; mm <<= 1) {
        #pragma unroll
        for (int m = 0; m < 4; ++m)
            #pragma unroll
            for (int j = 0; j < 4; ++j)
                s[m][j] += __shfl_xor(s[m][j], mm);
    }
    float* rp = (float*)Asm;   // reuse A LDS: [2][128] row partials
    if (lo == 0) {
        #pragma unroll
        for (int m = 0; m < 4; ++m)
            #pragma unroll
            for (int j = 0; j < 4; ++j)
                rp[nh * 128 + mh + m * 16 + hi * 4 + j] = s[m][j];
    }
    __syncthreads();
    if (t < MT) {
        int gr = m_base + t;
        if (gr < LSUP) {
            float o = rp[t] + rp[128 + t];
            if (img < NSUP && (gr / SEQ) == img) o = 0.f;
            Rall[(size_t)img * LSUP + gr] = o;
        }
    }
}

// ---------------------------------------------------------------------------
// Kernel 3: fused optimizer, 5 blocks x 1024 (one class per block).
// No barriers, no atomics: each block fully owns D[.][w]; the pre-zeroed
// D values themselves are the sync token (D provably > 0), written with
// release stores and spin-read with acquire until nonzero.
// ---------------------------------------------------------------------------
__global__ __launch_bounds__(1024) void opt_fused(
    const float* __restrict__ Rall,
    const int* __restrict__ labels,
    float* __restrict__ Dbufs,      // [16][125], pre-zeroed
    float* __restrict__ out)        // [75][5]
{
    __shared__ float Dsm[125];
    __shared__ float cfs[NSUP];
    __shared__ float red[16][NSUP];
    __shared__ float esm[BLOCK_W];
    __shared__ int lsm[NSUP];

    int w = blockIdx.x;             // class 0..4
    int t = threadIdx.x;
    int wave = t >> 6, lane = t & 63;
    bool act = t < BLOCK_W;
    int ls = w * BLOCK_W + t;

    float Rv[NSUP];
    #pragma unroll
    for (int b = 0; b < NSUP; ++b)
        Rv[b] = act ? Rall[(size_t)b * LSUP + ls] : 0.f;
    if (t < NSUP) lsm[t] = labels[t];

    float vv = 0.f;
    float e  = 1.f;                 // e^{v/T}

    auto pushD = [&](int step) {
        float part[NSUP];
        #pragma unroll
        for (int b = 0; b < NSUP; ++b) part[b] = e * Rv[b];
        #pragma unroll
        for (int b = 0; b < NSUP; ++b) {
            #pragma unroll
            for (int m = 32; m; m >>= 1) part[b] += __shfl_xor(part[b], m);
        }
        if (lane == 0) {
            #pragma unroll
            for (int b = 0; b < NSUP; ++b) red[wave][b] = part[b];
        }
        __syncthreads();
        if (t < NSUP) {
            float s = 0.f;
            #pragma unroll
            for (int k = 0; k < 16; ++k) s += red[k][t];
            __hip_atomic_store(&Dbufs[step * 125 + t * 5 + w], s,
                               __ATOMIC_RELEASE, __HIP_MEMORY_SCOPE_AGENT);
        }
    };

    pushD(0);    // e = 1

    for (int s = 0; s < OPT_STEPS; ++s) {
        if (t < 125) {
            float dv;
            do {
                dv = __hip_atomic_load(&Dbufs[s * 125 + t],
                                       __ATOMIC_ACQUIRE, __HIP_MEMORY_SCOPE_AGENT);
            } while (dv == 0.f);
            Dsm[t] = dv;
        }
        __syncthreads();
        if (t < NSUP) {
            int b = t;
            float Dsum = 0.f, Dw = 1.f;
            #pragma unroll
            for (int ww = 0; ww < 5; ++ww) {
                float d = Dsm[b * 5 + ww];
                Dsum += d;
                if (ww == w) Dw = d;
            }
            cfs[b] = ((Dw / Dsum) - (w == lsm[b] ? 1.f : 0.f)) * (INV_T / 25.f) / Dw;
        }
        __syncthreads();
        float g = 0.f;
        #pragma unroll
        for (int b = 0; b < NSUP; ++b) g += cfs[b] * Rv[b];
        if (act) {
            vv -= LR_F * e * g;
            e = __expf(vv * INV_T);
        }
        if (s + 1 < OPT_STEPS) {
            __syncthreads();        // cfs/red reuse protection
            pushD(s + 1);
        }
    }

    // ---- final prediction: out[qb][w] = log( sum e * R[25+qb][ls] ) ----
    esm[0] = 0.f;                   // (avoid unused-warning path; t<980 writes)
    if (act) esm[t] = e;
    __syncthreads();
    for (int qb = wave; qb < NQRY; qb += 16) {
        const float* R = Rall + (size_t)(NSUP + qb) * LSUP + w * BLOCK_W;
        float p = 0.f;
        for (int i = lane; i < BLOCK_W; i += 64) p += esm[i] * R[i];
        #pragma unroll
        for (int m = 32; m; m >>= 1) p += __shfl_xor(p, m);
        if (lane == 0) out[qb * 5 + w] = logf(p);
    }
}

// ---------------------------------------------------------------------------
extern "C" void kernel_launch(void* const* d_in, const int* in_sizes, int n_in,
                              void* d_out, int out_size, void* d_ws, size_t ws_size,
                              hipStream_t stream) {
    const float* sup_key = (const float*)d_in[0];   // [25,196,384]
    const float* sup_qry = (const float*)d_in[1];   // [25,196,384]
    const float* qry     = (const float*)d_in[2];   // [75,196,384]
    const int*   labels  = (const int*)d_in[3];     // [25]
    float* out = (float*)d_out;                     // [75,5]

    char* ws = (char*)d_ws;
    size_t off = 0;
    auto take = [&](size_t bytes) {
        char* p = ws + off;
        off = (off + bytes + 255) & ~(size_t)255;
        return p;
    };
    unsigned short* Kb   = (unsigned short*)take((size_t)LSUP_PAD * DIM * 2);
    unsigned short* Qall = (unsigned short*)take((size_t)NIMG * QROWS * DIM * 2);
    float*          Rall = (float*)take((size_t)NIMG * LSUP * 4);
    float*          Dbuf = (float*)take((size_t)(OPT_STEPS + 1) * 125 * 4);

    hipMemsetAsync(Dbuf, 0, (size_t)(OPT_STEPS + 1) * 125 * 4, stream);

    norm_k<<<LSUP_PAD / 4, 256, 0, stream>>>(sup_key, Kb);
    norm_q<<<dim3(QROWS / 4, NIMG), 256, 0, stream>>>(sup_qry, qry, Qall);

    fused_expsum_mfma<<<MTILES * NIMG, 256, 0, stream>>>(Kb, Qall, Rall);

    opt_fused<<<NW, 1024, 0, stream>>>(Rall, labels, Dbuf, out);
}

// Round 4
// 232.741 us; speedup vs baseline: 1.4043x; 1.4043x over previous
//
#include <hip/hip_runtime.h>
#include <hip/hip_bf16.h>

// ---- problem constants ----
#define NW 5
#define KS 5
#define SEQ 196
#define DIM 384
#define NSUP 25        // NW*KS support images
#define NQRY 75        // query images
#define NIMG 100       // NSUP + NQRY
#define LSUP 4900      // NSUP*SEQ support rows
#define LSUP_PAD 4992  // 39*128, zero-padded K rows
#define QROWS 208      // padded qs rows per image (13*16)
#define BLOCK_W 980    // KS*SEQ rows per class block
#define OPT_STEPS 15
#define MTILES 39      // LSUP_PAD / MT

static constexpr float TEMP_F = 0.0510310363f;
static constexpr float INV_T  = 1.0f / TEMP_F;   // ~19.5959
static constexpr float LR_F   = 0.1f;

typedef short v8s __attribute__((ext_vector_type(8)));   // 8 x bf16 frag (4 VGPRs)
typedef float v4f __attribute__((ext_vector_type(4)));   // 4 x f32 acc

__device__ inline unsigned short f2bf(float x) {
    unsigned int u = __float_as_uint(x);
    u += 0x7fffu + ((u >> 16) & 1u);
    return (unsigned short)(u >> 16);
}

// ---------------------------------------------------------------------------
// Kernel 1a: K-side normalize (pre-scaled by 1/T). Wave-per-row, no LDS/sync.
// ---------------------------------------------------------------------------
__global__ __launch_bounds__(256) void norm_k(const float* __restrict__ src,
                                              unsigned short* __restrict__ dst) {
    int row = blockIdx.x * 4 + (threadIdx.x >> 6);
    int l = threadIdx.x & 63;
    unsigned short* out = dst + (size_t)row * DIM;
    if (row >= LSUP) {
        #pragma unroll
        for (int k = 0; k < 6; ++k) out[l + 64 * k] = 0;
        return;
    }
    const float* in = src + (size_t)row * DIM;
    float x[6];
    #pragma unroll
    for (int k = 0; k < 6; ++k) x[k] = in[l + 64 * k];
    float s = 0.f;
    #pragma unroll
    for (int k = 0; k < 6; ++k) s += x[k] * x[k];
    #pragma unroll
    for (int m = 1; m < 64; m <<= 1) s += __shfl_xor(s, m);
    float sc = INV_T / fmaxf(sqrtf(s), 1e-8f);
    #pragma unroll
    for (int k = 0; k < 6; ++k) out[l + 64 * k] = f2bf(x[k] * sc);
}

// ---------------------------------------------------------------------------
// Kernel 1b: Q-side normalize into padded [100][208][384]. Wave-per-row.
// ---------------------------------------------------------------------------
__global__ __launch_bounds__(256) void norm_q(const float* __restrict__ supq,
                                              const float* __restrict__ qry,
                                              unsigned short* __restrict__ dst) {
    int r = blockIdx.x * 4 + (threadIdx.x >> 6);   // 0..207
    int img = blockIdx.y;                          // 0..99
    int l = threadIdx.x & 63;
    unsigned short* out = dst + ((size_t)img * QROWS + r) * DIM;
    if (r >= SEQ) {
        #pragma unroll
        for (int k = 0; k < 6; ++k) out[l + 64 * k] = 0;
        return;
    }
    const float* in = (img < NSUP)
        ? supq + ((size_t)img * SEQ + r) * DIM
        : qry  + ((size_t)(img - NSUP) * SEQ + r) * DIM;
    float x[6];
    #pragma unroll
    for (int k = 0; k < 6; ++k) x[k] = in[l + 64 * k];
    float s = 0.f;
    #pragma unroll
    for (int k = 0; k < 6; ++k) s += x[k] * x[k];
    #pragma unroll
    for (int m = 1; m < 64; m <<= 1) s += __shfl_xor(s, m);
    float sc = 1.0f / fmaxf(sqrtf(s), 1e-8f);
    #pragma unroll
    for (int k = 0; k < 6; ++k) out[l + 64 * k] = f2bf(x[k] * sc);
}

// ---------------------------------------------------------------------------
// GEMM body: MFMA fused exp-sum, global_load_lds + XOR swizzle, XCD remap.
// 2M x 2N wave split. Parameterized by image base and grid size (bijective
// m204 remap computed from constexpr NWG).
// ---------------------------------------------------------------------------
#define MT  128
#define NTP 208
#define KCC 64

__device__ __forceinline__ void gload16(const void* g, void* l) {
    __builtin_amdgcn_global_load_lds(
        (__attribute__((address_space(1))) void*)g,
        (__attribute__((address_space(3))) void*)l, 16, 0, 0);
}

template<int IMG_BASE, int NWG>
__device__ __forceinline__ void gemm_body(
    int gid,
    const unsigned short* __restrict__ Kb,     // [4992][384] bf16, pre /T
    const unsigned short* __restrict__ Qall,   // [100][208][384] bf16
    float* __restrict__ Rall,
    unsigned short* Asm, unsigned short* Bsm)
{
    int t = threadIdx.x;

    // bijective XCD-aware remap (m204)
    constexpr int qq = NWG >> 3;
    constexpr int rr = NWG & 7;
    int xcd = gid & 7;
    int sub = gid >> 3;
    int L = (xcd < rr ? xcd * (qq + 1) : rr * (qq + 1) + (xcd - rr) * qq) + sub;
    int img = IMG_BASE + L / MTILES;
    int m_base = (L % MTILES) * MT;

    const unsigned short* Qimg = Qall + (size_t)img * (QROWS * DIM);

    int wv = t >> 6;        // wave 0..3
    int l  = t & 63;
    int lo = l & 15;        // MFMA frag row/col index
    int hi = l >> 4;        // k-group
    int mh = (wv >> 1) * 64;   // M-half base row
    int nh = wv & 1;           // N-half

    int srow = l >> 3;
    int skp  = (l & 7) ^ srow;      // involution within 8-slot row
    const unsigned short* aSrc = Kb   + (size_t)(m_base + wv * 32 + srow) * DIM + skp * 8;
    const unsigned short* bSrc = Qimg + (size_t)srow * DIM + skp * 8;

    v4f acc[4][7];
    #pragma unroll
    for (int m = 0; m < 4; ++m)
        #pragma unroll
        for (int n = 0; n < 7; ++n)
            acc[m][n] = (v4f){0.f, 0.f, 0.f, 0.f};

    for (int kb = 0; kb < DIM; kb += KCC) {
        #pragma unroll
        for (int j = 0; j < 4; ++j)
            gload16(aSrc + (size_t)j * 8 * DIM + kb,
                    Asm + (wv * 32 + j * 8) * KCC);
        #pragma unroll
        for (int jj = 0; jj < 7; ++jj) {
            int j = wv + jj * 4;
            if (j < 26)
                gload16(bSrc + (size_t)j * 8 * DIM + kb,
                        Bsm + j * 8 * KCC);
        }
        __syncthreads();   // drains vmcnt before LDS reads

        const unsigned short* Ar = Asm + (mh + lo) * KCC;
        const unsigned short* Br = Bsm + (nh * 112 + lo) * KCC;
        #pragma unroll
        for (int kk = 0; kk < 2; ++kk) {
            int koff = ((hi + 4 * kk) ^ (lo & 7)) * 8;   // swizzled k-slot
            v8s a0 = *(const v8s*)(Ar + koff);
            v8s a1 = *(const v8s*)(Ar + 16 * KCC + koff);
            v8s a2 = *(const v8s*)(Ar + 32 * KCC + koff);
            v8s a3 = *(const v8s*)(Ar + 48 * KCC + koff);
            #pragma unroll
            for (int n = 0; n < 7; ++n) {
                if (nh == 0 || n < 6) {   // wave-uniform
                    v8s bb = *(const v8s*)(Br + n * 16 * KCC + koff);
                    acc[0][n] = __builtin_amdgcn_mfma_f32_16x16x32_bf16(a0, bb, acc[0][n], 0, 0, 0);
                    acc[1][n] = __builtin_amdgcn_mfma_f32_16x16x32_bf16(a1, bb, acc[1][n], 0, 0, 0);
                    acc[2][n] = __builtin_amdgcn_mfma_f32_16x16x32_bf16(a2, bb, acc[2][n], 0, 0, 0);
                    acc[3][n] = __builtin_amdgcn_mfma_f32_16x16x32_bf16(a3, bb, acc[3][n], 0, 0, 0);
                }
            }
        }
        __syncthreads();
    }

    // epilogue: exp + per-wave column-half sums. C/D: col=lo, row=hi*4+reg.
    float s[4][4];
    #pragma unroll
    for (int m = 0; m < 4; ++m)
        #pragma unroll
        for (int j = 0; j < 4; ++j) s[m][j] = 0.f;
    #pragma unroll
    for (int n = 0; n < 7; ++n) {
        if (nh == 0 || n < 6) {
            bool ok = ((nh * 7 + n) * 16 + lo) < SEQ;
            #pragma unroll
            for (int m = 0; m < 4; ++m)
                #pragma unroll
                for (int j = 0; j < 4; ++j)
                    s[m][j] += ok ? __expf(acc[m][n][j]) : 0.f;
        }
    }
    #pragma unroll
    for (int mm = 1; mm < 16; mm <<= 1) {
        #pragma unroll
        for (int m = 0; m < 4; ++m)
            #pragma unroll
            for (int j = 0; j < 4; ++j)
                s[m][j] += __shfl_xor(s[m][j], mm);
    }
    float* rp = (float*)Asm;   // reuse A LDS: [2][128] row partials
    if (lo == 0) {
        #pragma unroll
        for (int m = 0; m < 4; ++m)
            #pragma unroll
            for (int j = 0; j < 4; ++j)
                rp[nh * 128 + mh + m * 16 + hi * 4 + j] = s[m][j];
    }
    __syncthreads();
    if (t < MT) {
        int gr = m_base + t;
        if (gr < LSUP) {
            float o = rp[t] + rp[128 + t];
            if (img < NSUP && (gr / SEQ) == img) o = 0.f;
            Rall[(size_t)img * LSUP + gr] = o;
        }
    }
}

// ---------------------------------------------------------------------------
// Kernel 2a: support-image GEMM (975 blocks). Runs before the mega kernel
// so the optimizer blocks in the mega kernel see complete support R.
// ---------------------------------------------------------------------------
__global__ __launch_bounds__(256, 3) void gemm_support(
    const unsigned short* __restrict__ Kb,
    const unsigned short* __restrict__ Qall,
    float* __restrict__ Rall)
{
    __shared__ __align__(16) unsigned short Asm[MT * KCC];
    __shared__ __align__(16) unsigned short Bsm[NTP * KCC];
    gemm_body<0, NSUP * MTILES>(blockIdx.x, Kb, Qall, Rall, Asm, Bsm);
}

// ---------------------------------------------------------------------------
// Kernel 2b: MEGA kernel. Blocks 0..4: the optimizer (one class each,
// 256 threads, 4 rows/thread register-resident, cross-block exchange via
// per-block seq flags + single-wave pollers). Blocks 5..2929: query GEMM.
// Opt blocks are dispatched first -> co-resident -> overlap with the GEMM.
// ---------------------------------------------------------------------------
__global__ __launch_bounds__(256, 3) void mega(
    const unsigned short* __restrict__ Kb,
    const unsigned short* __restrict__ Qall,
    float* __restrict__ Rall,
    const int* __restrict__ labels,
    float* __restrict__ Dbufs,      // [16][125], pre-zeroed
    int* __restrict__ flags,        // [8], pre-zeroed; flags[w] = #pushD done
    float* __restrict__ e_out)      // [4900] final e^{v/T}
{
    __shared__ __align__(16) unsigned short Asm[MT * KCC];
    __shared__ __align__(16) unsigned short Bsm[NTP * KCC];

    if (blockIdx.x >= NW) {
        gemm_body<NSUP, NQRY * MTILES>((int)blockIdx.x - NW, Kb, Qall, Rall, Asm, Bsm);
        return;
    }

    // ---- optimizer block for class w ----
    float* sh  = (float*)Asm;
    float* red = sh;              // [4][25]
    float* cfs = sh + 100;        // [25]
    float* Dsm = sh + 128;        // [125]
    int*   lsm = (int*)(sh + 256);// [25]

    int w = blockIdx.x;
    int t = threadIdx.x;
    int wave = t >> 6, lane = t & 63;

    // rows r = t + 256k, k<4 (k=3 valid only for t<212); inactive rows -> 0
    float Rv[4][NSUP];
    #pragma unroll
    for (int b = 0; b < NSUP; ++b) {
        const float* Rb = Rall + (size_t)b * LSUP + w * BLOCK_W;
        Rv[0][b] = Rb[t];
        Rv[1][b] = Rb[t + 256];
        Rv[2][b] = Rb[t + 512];
        Rv[3][b] = (t < BLOCK_W - 768) ? Rb[t + 768] : 0.f;
    }
    if (t < NSUP) lsm[t] = labels[t];

    float e0 = 1.f, e1 = 1.f, e2 = 1.f, e3 = 1.f;
    float v0 = 0.f, v1 = 0.f, v2 = 0.f, v3 = 0.f;

    auto pushD = [&](int step) {
        float part[NSUP];
        #pragma unroll
        for (int b = 0; b < NSUP; ++b)
            part[b] = e0 * Rv[0][b] + e1 * Rv[1][b] + e2 * Rv[2][b] + e3 * Rv[3][b];
        #pragma unroll
        for (int b = 0; b < NSUP; ++b) {
            #pragma unroll
            for (int m = 32; m; m >>= 1) part[b] += __shfl_xor(part[b], m);
        }
        if (lane == 0) {
            #pragma unroll
            for (int b = 0; b < NSUP; ++b) red[wave * NSUP + b] = part[b];
        }
        __syncthreads();
        if (t < NSUP) {
            float s = red[t] + red[NSUP + t] + red[2 * NSUP + t] + red[3 * NSUP + t];
            __hip_atomic_store(&Dbufs[step * 125 + t * 5 + w], s,
                               __ATOMIC_RELEASE, __HIP_MEMORY_SCOPE_AGENT);
        }
        __syncthreads();   // payload stores drained (vmcnt 0) before flag
        if (t == 0)
            __hip_atomic_store(&flags[w], step + 1,
                               __ATOMIC_RELEASE, __HIP_MEMORY_SCOPE_AGENT);
    };

    pushD(0);    // e = 1

    for (int s = 0; s < OPT_STEPS; ++s) {
        // wait for all 5 blocks' step-s D: one polling wave, lanes 0..4
        if (wave == 0) {
            for (;;) {
                int f = (lane < NW)
                    ? __hip_atomic_load(&flags[lane], __ATOMIC_ACQUIRE, __HIP_MEMORY_SCOPE_AGENT)
                    : 0x7fffffff;
                if (__all(f >= s + 1)) break;
                __builtin_amdgcn_s_sleep(1);
            }
        }
        __syncthreads();
        if (t < 125)
            Dsm[t] = __hip_atomic_load(&Dbufs[s * 125 + t],
                                       __ATOMIC_ACQUIRE, __HIP_MEMORY_SCOPE_AGENT);
        __syncthreads();
        if (t < NSUP) {
            float Dsum = 0.f, Dw = 1.f;
            #pragma unroll
            for (int ww = 0; ww < NW; ++ww) {
                float d = Dsm[t * 5 + ww];
                Dsum += d;
                if (ww == w) Dw = d;
            }
            cfs[t] = ((Dw / Dsum) - (w == lsm[t] ? 1.f : 0.f)) * (INV_T / 25.f) / Dw;
        }
        __syncthreads();
        float g0 = 0.f, g1 = 0.f, g2 = 0.f, g3 = 0.f;
        #pragma unroll
        for (int b = 0; b < NSUP; ++b) {
            float c = cfs[b];
            g0 += c * Rv[0][b];
            g1 += c * Rv[1][b];
            g2 += c * Rv[2][b];
            g3 += c * Rv[3][b];
        }
        v0 -= LR_F * e0 * g0; e0 = __expf(v0 * INV_T);
        v1 -= LR_F * e1 * g1; e1 = __expf(v1 * INV_T);
        v2 -= LR_F * e2 * g2; e2 = __expf(v2 * INV_T);
        v3 -= LR_F * e3 * g3; e3 = __expf(v3 * INV_T);
        __syncthreads();      // red/Dsm/cfs reuse protection
        if (s + 1 < OPT_STEPS) pushD(s + 1);
    }

    // export e (rows beyond BLOCK_W never read)
    float* eo = e_out + w * BLOCK_W;
    eo[t]       = e0;
    eo[t + 256] = e1;
    eo[t + 512] = e2;
    if (t < BLOCK_W - 768) eo[t + 768] = e3;
}

// ---------------------------------------------------------------------------
// Kernel 3: final prediction. 375 blocks (qb*5+w) x 256.
// ---------------------------------------------------------------------------
__global__ __launch_bounds__(256) void final_pred(const float* __restrict__ Rall,
                                                  const float* __restrict__ e_out,
                                                  float* __restrict__ out) {
    __shared__ float ws[4];
    int blk = blockIdx.x;
    int qb = blk / 5, w = blk % 5;
    const float* R  = Rall + (size_t)(NSUP + qb) * LSUP + w * BLOCK_W;
    const float* eb = e_out + w * BLOCK_W;
    int t = threadIdx.x;
    float p = 0.f;
    for (int i = t; i < BLOCK_W; i += 256) p += eb[i] * R[i];
    #pragma unroll
    for (int m = 32; m; m >>= 1) p += __shfl_xor(p, m);
    if ((t & 63) == 0) ws[t >> 6] = p;
    __syncthreads();
    if (t == 0) out[blk] = logf(ws[0] + ws[1] + ws[2] + ws[3]);
}

// ---------------------------------------------------------------------------
extern "C" void kernel_launch(void* const* d_in, const int* in_sizes, int n_in,
                              void* d_out, int out_size, void* d_ws, size_t ws_size,
                              hipStream_t stream) {
    const float* sup_key = (const float*)d_in[0];   // [25,196,384]
    const float* sup_qry = (const float*)d_in[1];   // [25,196,384]
    const float* qry     = (const float*)d_in[2];   // [75,196,384]
    const int*   labels  = (const int*)d_in[3];     // [25]
    float* out = (float*)d_out;                     // [75,5]

    char* ws = (char*)d_ws;
    size_t off = 0;
    auto take = [&](size_t bytes) {
        char* p = ws + off;
        off = (off + bytes + 255) & ~(size_t)255;
        return p;
    };
    unsigned short* Kb   = (unsigned short*)take((size_t)LSUP_PAD * DIM * 2);
    unsigned short* Qall = (unsigned short*)take((size_t)NIMG * QROWS * DIM * 2);
    float*          Rall = (float*)take((size_t)NIMG * LSUP * 4);
    float*          Dbuf = (float*)take(((size_t)(OPT_STEPS + 1) * 125 + 32) * 4);
    float*          eout = (float*)take((size_t)LSUP * 4);
    int*            flags = (int*)(Dbuf + (OPT_STEPS + 1) * 125);

    hipMemsetAsync(Dbuf, 0, ((size_t)(OPT_STEPS + 1) * 125 + 32) * 4, stream);

    norm_k<<<LSUP_PAD / 4, 256, 0, stream>>>(sup_key, Kb);
    norm_q<<<dim3(QROWS / 4, NIMG), 256, 0, stream>>>(sup_qry, qry, Qall);

    gemm_support<<<NSUP * MTILES, 256, 0, stream>>>(Kb, Qall, Rall);

    mega<<<NW + NQRY * MTILES, 256, 0, stream>>>(Kb, Qall, Rall, labels, Dbuf, flags, eout);

    final_pred<<<NQRY * NW, 256, 0, stream>>>(Rall, eout, out);
}

// Round 5
// 219.814 us; speedup vs baseline: 1.4869x; 1.0588x over previous
//
#include <hip/hip_runtime.h>
#include <hip/hip_bf16.h>

// ---- problem constants ----
#define NW 5
#define KS 5
#define SEQ 196
#define DIM 384
#define NSUP 25        // NW*KS support images
#define NQRY 75        // query images
#define NIMG 100       // NSUP + NQRY
#define LSUP 4900      // NSUP*SEQ support rows
#define LSUP_PAD 4992  // 39*128, zero-padded K rows
#define QROWS 208      // padded qs rows per image (13*16)
#define BLOCK_W 980    // KS*SEQ rows per class block
#define OPT_STEPS 15
#define MTILES 39      // LSUP_PAD / MT

static constexpr float TEMP_F = 0.0510310363f;
static constexpr float INV_T  = 1.0f / TEMP_F;   // ~19.5959
static constexpr float LR_F   = 0.1f;

typedef short v8s __attribute__((ext_vector_type(8)));   // 8 x bf16 frag (4 VGPRs)
typedef float v4f __attribute__((ext_vector_type(4)));   // 4 x f32 acc

__device__ inline unsigned short f2bf(float x) {
    unsigned int u = __float_as_uint(x);
    u += 0x7fffu + ((u >> 16) & 1u);
    return (unsigned short)(u >> 16);
}

// ---------------------------------------------------------------------------
// Kernel 1: fused normalize. Wave-per-row.
// Rows [0, LSUP_PAD): K-side (pre-scaled 1/T, zero-padded tail).
// Rows [LSUP_PAD, LSUP_PAD + NIMG*QROWS): Q-side padded [100][208][384].
// ---------------------------------------------------------------------------
__global__ __launch_bounds__(256) void norm_all(const float* __restrict__ supk,
                                                const float* __restrict__ supq,
                                                const float* __restrict__ qry,
                                                unsigned short* __restrict__ Kb,
                                                unsigned short* __restrict__ Qall) {
    int R = blockIdx.x * 4 + (threadIdx.x >> 6);
    int l = threadIdx.x & 63;
    unsigned short* out;
    const float* in;
    float scale;
    if (R < LSUP_PAD) {
        out = Kb + (size_t)R * DIM;
        if (R >= LSUP) {
            #pragma unroll
            for (int k = 0; k < 6; ++k) out[l + 64 * k] = 0;
            return;
        }
        in = supk + (size_t)R * DIM;
        scale = INV_T;
    } else {
        int i = R - LSUP_PAD;
        int img = i / QROWS;
        int r = i - img * QROWS;
        out = Qall + (size_t)i * DIM;
        if (r >= SEQ) {
            #pragma unroll
            for (int k = 0; k < 6; ++k) out[l + 64 * k] = 0;
            return;
        }
        in = (img < NSUP)
            ? supq + ((size_t)img * SEQ + r) * DIM
            : qry  + ((size_t)(img - NSUP) * SEQ + r) * DIM;
        scale = 1.0f;
    }
    float x[6];
    #pragma unroll
    for (int k = 0; k < 6; ++k) x[k] = in[l + 64 * k];
    float s = 0.f;
    #pragma unroll
    for (int k = 0; k < 6; ++k) s += x[k] * x[k];
    #pragma unroll
    for (int m = 1; m < 64; m <<= 1) s += __shfl_xor(s, m);
    float sc = scale / fmaxf(sqrtf(s), 1e-8f);
    #pragma unroll
    for (int k = 0; k < 6; ++k) out[l + 64 * k] = f2bf(x[k] * sc);
}

// ---------------------------------------------------------------------------
// GEMM body: MFMA fused exp-sum, global_load_lds + XOR swizzle, XCD remap.
// 2M x 2N wave split.
// ---------------------------------------------------------------------------
#define MT  128
#define NTP 208
#define KCC 64

__device__ __forceinline__ void gload16(const void* g, void* l) {
    __builtin_amdgcn_global_load_lds(
        (__attribute__((address_space(1))) void*)g,
        (__attribute__((address_space(3))) void*)l, 16, 0, 0);
}

template<int IMG_BASE, int NWG>
__device__ __forceinline__ void gemm_body(
    int gid,
    const unsigned short* __restrict__ Kb,     // [4992][384] bf16, pre /T
    const unsigned short* __restrict__ Qall,   // [100][208][384] bf16
    float* __restrict__ Rall,
    unsigned short* Asm, unsigned short* Bsm)
{
    int t = threadIdx.x;

    // bijective XCD-aware remap (m204)
    constexpr int qq = NWG >> 3;
    constexpr int rr = NWG & 7;
    int xcd = gid & 7;
    int sub = gid >> 3;
    int L = (xcd < rr ? xcd * (qq + 1) : rr * (qq + 1) + (xcd - rr) * qq) + sub;
    int img = IMG_BASE + L / MTILES;
    int m_base = (L % MTILES) * MT;

    const unsigned short* Qimg = Qall + (size_t)img * (QROWS * DIM);

    int wv = t >> 6;        // wave 0..3
    int l  = t & 63;
    int lo = l & 15;        // MFMA frag row/col index
    int hi = l >> 4;        // k-group
    int mh = (wv >> 1) * 64;   // M-half base row
    int nh = wv & 1;           // N-half

    int srow = l >> 3;
    int skp  = (l & 7) ^ srow;      // involution within 8-slot row
    const unsigned short* aSrc = Kb   + (size_t)(m_base + wv * 32 + srow) * DIM + skp * 8;
    const unsigned short* bSrc = Qimg + (size_t)srow * DIM + skp * 8;

    v4f acc[4][7];
    #pragma unroll
    for (int m = 0; m < 4; ++m)
        #pragma unroll
        for (int n = 0; n < 7; ++n)
            acc[m][n] = (v4f){0.f, 0.f, 0.f, 0.f};

    for (int kb = 0; kb < DIM; kb += KCC) {
        #pragma unroll
        for (int j = 0; j < 4; ++j)
            gload16(aSrc + (size_t)j * 8 * DIM + kb,
                    Asm + (wv * 32 + j * 8) * KCC);
        #pragma unroll
        for (int jj = 0; jj < 7; ++jj) {
            int j = wv + jj * 4;
            if (j < 26)
                gload16(bSrc + (size_t)j * 8 * DIM + kb,
                        Bsm + j * 8 * KCC);
        }
        __syncthreads();   // drains vmcnt before LDS reads

        const unsigned short* Ar = Asm + (mh + lo) * KCC;
        const unsigned short* Br = Bsm + (nh * 112 + lo) * KCC;
        #pragma unroll
        for (int kk = 0; kk < 2; ++kk) {
            int koff = ((hi + 4 * kk) ^ (lo & 7)) * 8;   // swizzled k-slot
            v8s a0 = *(const v8s*)(Ar + koff);
            v8s a1 = *(const v8s*)(Ar + 16 * KCC + koff);
            v8s a2 = *(const v8s*)(Ar + 32 * KCC + koff);
            v8s a3 = *(const v8s*)(Ar + 48 * KCC + koff);
            #pragma unroll
            for (int n = 0; n < 7; ++n) {
                if (nh == 0 || n < 6) {   // wave-uniform
                    v8s bb = *(const v8s*)(Br + n * 16 * KCC + koff);
                    acc[0][n] = __builtin_amdgcn_mfma_f32_16x16x32_bf16(a0, bb, acc[0][n], 0, 0, 0);
                    acc[1][n] = __builtin_amdgcn_mfma_f32_16x16x32_bf16(a1, bb, acc[1][n], 0, 0, 0);
                    acc[2][n] = __builtin_amdgcn_mfma_f32_16x16x32_bf16(a2, bb, acc[2][n], 0, 0, 0);
                    acc[3][n] = __builtin_amdgcn_mfma_f32_16x16x32_bf16(a3, bb, acc[3][n], 0, 0, 0);
                }
            }
        }
        __syncthreads();
    }

    // epilogue: exp + per-wave column-half sums. C/D: col=lo, row=hi*4+reg.
    float s[4][4];
    #pragma unroll
    for (int m = 0; m < 4; ++m)
        #pragma unroll
        for (int j = 0; j < 4; ++j) s[m][j] = 0.f;
    #pragma unroll
    for (int n = 0; n < 7; ++n) {
        if (nh == 0 || n < 6) {
            bool ok = ((nh * 7 + n) * 16 + lo) < SEQ;
            #pragma unroll
            for (int m = 0; m < 4; ++m)
                #pragma unroll
                for (int j = 0; j < 4; ++j)
                    s[m][j] += ok ? __expf(acc[m][n][j]) : 0.f;
        }
    }
    #pragma unroll
    for (int mm = 1; mm < 16; mm <<= 1) {
        #pragma unroll
        for (int m = 0; m < 4; ++m)
            #pragma unroll
            for (int j = 0; j < 4; ++j)
                s[m][j] += __shfl_xor(s[m][j], mm);
    }
    float* rp = (float*)Asm;   // reuse A LDS: [2][128] row partials
    if (lo == 0) {
        #pragma unroll
        for (int m = 0; m < 4; ++m)
            #pragma unroll
            for (int j = 0; j < 4; ++j)
                rp[nh * 128 + mh + m * 16 + hi * 4 + j] = s[m][j];
    }
    __syncthreads();
    if (t < MT) {
        int gr = m_base + t;
        if (gr < LSUP) {
            float o = rp[t] + rp[128 + t];
            if (img < NSUP && (gr / SEQ) == img) o = 0.f;
            Rall[(size_t)img * LSUP + gr] = o;
        }
    }
}

// ---------------------------------------------------------------------------
// Kernel 2a: support-image GEMM (975 blocks).
// ---------------------------------------------------------------------------
__global__ __launch_bounds__(256, 3) void gemm_support(
    const unsigned short* __restrict__ Kb,
    const unsigned short* __restrict__ Qall,
    float* __restrict__ Rall)
{
    __shared__ __align__(16) unsigned short Asm[MT * KCC];
    __shared__ __align__(16) unsigned short Bsm[NTP * KCC];
    gemm_body<0, NSUP * MTILES>(blockIdx.x, Kb, Qall, Rall, Asm, Bsm);
}

// ---------------------------------------------------------------------------
// Kernel 2b: MEGA kernel. Blocks 0..4: optimizer (one class each). Blocks
// 5..2929: query GEMM. Cross-block exchange uses ONLY relaxed agent-scope
// (sc1) atomics — no acquire/release, hence no buffer_inv / buffer_wbl2
// L2-maintenance storms (round-4 lesson: those thrashed the co-resident
// GEMM's L2 and made each exchange ~8 us). Ordering: payload stores ->
// __syncthreads (drains vmcnt -> acked at coherence point) -> flag store.
// ---------------------------------------------------------------------------
__global__ __launch_bounds__(256, 3) void mega(
    const unsigned short* __restrict__ Kb,
    const unsigned short* __restrict__ Qall,
    float* __restrict__ Rall,
    const int* __restrict__ labels,
    float* __restrict__ Dbufs,      // [16][125], pre-zeroed
    int* __restrict__ flags,        // [8], pre-zeroed; flags[w] = #pushD done
    float* __restrict__ e_out)      // [4900] final e^{v/T}
{
    __shared__ __align__(16) unsigned short Asm[MT * KCC];
    __shared__ __align__(16) unsigned short Bsm[NTP * KCC];

    if (blockIdx.x >= NW) {
        gemm_body<NSUP, NQRY * MTILES>((int)blockIdx.x - NW, Kb, Qall, Rall, Asm, Bsm);
        return;
    }

    // ---- optimizer block for class w ----
    float* sh  = (float*)Asm;
    float* red = sh;              // [4][25]
    float* cfs = sh + 100;        // [25]
    float* Dsm = sh + 128;        // [125]
    int*   lsm = (int*)(sh + 256);// [25]

    int w = blockIdx.x;
    int t = threadIdx.x;
    int wave = t >> 6, lane = t & 63;

    // rows r = t + 256k, k<4 (k=3 valid only for t<212); inactive rows -> 0
    float Rv[4][NSUP];
    #pragma unroll
    for (int b = 0; b < NSUP; ++b) {
        const float* Rb = Rall + (size_t)b * LSUP + w * BLOCK_W;
        Rv[0][b] = Rb[t];
        Rv[1][b] = Rb[t + 256];
        Rv[2][b] = Rb[t + 512];
        Rv[3][b] = (t < BLOCK_W - 768) ? Rb[t + 768] : 0.f;
    }
    if (t < NSUP) lsm[t] = labels[t];

    float e0 = 1.f, e1 = 1.f, e2 = 1.f, e3 = 1.f;
    float v0 = 0.f, v1 = 0.f, v2 = 0.f, v3 = 0.f;

    auto pushD = [&](int step) {
        float part[NSUP];
        #pragma unroll
        for (int b = 0; b < NSUP; ++b)
            part[b] = e0 * Rv[0][b] + e1 * Rv[1][b] + e2 * Rv[2][b] + e3 * Rv[3][b];
        #pragma unroll
        for (int b = 0; b < NSUP; ++b) {
            #pragma unroll
            for (int m = 32; m; m >>= 1) part[b] += __shfl_xor(part[b], m);
        }
        if (lane == 0) {
            #pragma unroll
            for (int b = 0; b < NSUP; ++b) red[wave * NSUP + b] = part[b];
        }
        __syncthreads();
        if (t < NSUP) {
            float s = red[t] + red[NSUP + t] + red[2 * NSUP + t] + red[3 * NSUP + t];
            __hip_atomic_store(&Dbufs[step * 125 + t * 5 + w], s,
                               __ATOMIC_RELAXED, __HIP_MEMORY_SCOPE_AGENT);
        }
        __syncthreads();   // vmcnt(0) drain: payload acked at coherence point
        if (t == 0)
            __hip_atomic_store(&flags[w], step + 1,
                               __ATOMIC_RELAXED, __HIP_MEMORY_SCOPE_AGENT);
    };

    pushD(0);    // e = 1

    for (int s = 0; s < OPT_STEPS; ++s) {
        // wait for all 5 blocks' step-s D: one polling wave, lanes 0..4
        if (wave == 0) {
            for (;;) {
                int f = (lane < NW)
                    ? __hip_atomic_load(&flags[lane], __ATOMIC_RELAXED, __HIP_MEMORY_SCOPE_AGENT)
                    : 0x7fffffff;
                if (__all(f >= s + 1)) break;
                __builtin_amdgcn_s_sleep(1);
            }
        }
        __syncthreads();
        if (t < 125)
            Dsm[t] = __hip_atomic_load(&Dbufs[s * 125 + t],
                                       __ATOMIC_RELAXED, __HIP_MEMORY_SCOPE_AGENT);
        __syncthreads();
        if (t < NSUP) {
            float Dsum = 0.f, Dw = 1.f;
            #pragma unroll
            for (int ww = 0; ww < NW; ++ww) {
                float d = Dsm[t * 5 + ww];
                Dsum += d;
                if (ww == w) Dw = d;
            }
            cfs[t] = ((Dw / Dsum) - (w == lsm[t] ? 1.f : 0.f)) * (INV_T / 25.f) / Dw;
        }
        __syncthreads();
        float g0 = 0.f, g1 = 0.f, g2 = 0.f, g3 = 0.f;
        #pragma unroll
        for (int b = 0; b < NSUP; ++b) {
            float c = cfs[b];
            g0 += c * Rv[0][b];
            g1 += c * Rv[1][b];
            g2 += c * Rv[2][b];
            g3 += c * Rv[3][b];
        }
        v0 -= LR_F * e0 * g0; e0 = __expf(v0 * INV_T);
        v1 -= LR_F * e1 * g1; e1 = __expf(v1 * INV_T);
        v2 -= LR_F * e2 * g2; e2 = __expf(v2 * INV_T);
        v3 -= LR_F * e3 * g3; e3 = __expf(v3 * INV_T);
        __syncthreads();      // red/Dsm/cfs reuse protection
        if (s + 1 < OPT_STEPS) pushD(s + 1);
    }

    // export e (rows beyond BLOCK_W never read)
    float* eo = e_out + w * BLOCK_W;
    eo[t]       = e0;
    eo[t + 256] = e1;
    eo[t + 512] = e2;
    if (t < BLOCK_W - 768) eo[t + 768] = e3;
}

// ---------------------------------------------------------------------------
// Kernel 3: final prediction. 375 blocks (qb*5+w) x 256.
// ---------------------------------------------------------------------------
__global__ __launch_bounds__(256) void final_pred(const float* __restrict__ Rall,
                                                  const float* __restrict__ e_out,
                                                  float* __restrict__ out) {
    __shared__ float ws[4];
    int blk = blockIdx.x;
    int qb = blk / 5, w = blk % 5;
    const float* R  = Rall + (size_t)(NSUP + qb) * LSUP + w * BLOCK_W;
    const float* eb = e_out + w * BLOCK_W;
    int t = threadIdx.x;
    float p = 0.f;
    for (int i = t; i < BLOCK_W; i += 256) p += eb[i] * R[i];
    #pragma unroll
    for (int m = 32; m; m >>= 1) p += __shfl_xor(p, m);
    if ((t & 63) == 0) ws[t >> 6] = p;
    __syncthreads();
    if (t == 0) out[blk] = logf(ws[0] + ws[1] + ws[2] + ws[3]);
}

// ---------------------------------------------------------------------------
extern "C" void kernel_launch(void* const* d_in, const int* in_sizes, int n_in,
                              void* d_out, int out_size, void* d_ws, size_t ws_size,
                              hipStream_t stream) {
    const float* sup_key = (const float*)d_in[0];   // [25,196,384]
    const float* sup_qry = (const float*)d_in[1];   // [25,196,384]
    const float* qry     = (const float*)d_in[2];   // [75,196,384]
    const int*   labels  = (const int*)d_in[3];     // [25]
    float* out = (float*)d_out;                     // [75,5]

    char* ws = (char*)d_ws;
    size_t off = 0;
    auto take = [&](size_t bytes) {
        char* p = ws + off;
        off = (off + bytes + 255) & ~(size_t)255;
        return p;
    };
    unsigned short* Kb   = (unsigned short*)take((size_t)LSUP_PAD * DIM * 2);
    unsigned short* Qall = (unsigned short*)take((size_t)NIMG * QROWS * DIM * 2);
    float*          Rall = (float*)take((size_t)NIMG * LSUP * 4);
    float*          Dbuf = (float*)take(((size_t)(OPT_STEPS + 1) * 125 + 32) * 4);
    float*          eout = (float*)take((size_t)LSUP * 4);
    int*            flags = (int*)(Dbuf + (OPT_STEPS + 1) * 125);

    hipMemsetAsync(Dbuf, 0, ((size_t)(OPT_STEPS + 1) * 125 + 32) * 4, stream);

    norm_all<<<(LSUP_PAD + NIMG * QROWS) / 4, 256, 0, stream>>>(
        sup_key, sup_qry, qry, Kb, Qall);

    gemm_support<<<NSUP * MTILES, 256, 0, stream>>>(Kb, Qall, Rall);

    mega<<<NW + NQRY * MTILES, 256, 0, stream>>>(Kb, Qall, Rall, labels, Dbuf, flags, eout);

    final_pred<<<NQRY * NW, 256, 0, stream>>>(Rall, eout, out);
}

// Round 6
// 219.633 us; speedup vs baseline: 1.4881x; 1.0008x over previous
//
#include <hip/hip_runtime.h>
#include <hip/hip_bf16.h>

// ---- problem constants ----
#define NW 5
#define KS 5
#define SEQ 196
#define DIM 384
#define NSUP 25        // NW*KS support images
#define NQRY 75        // query images
#define NIMG 100       // NSUP + NQRY
#define LSUP 4900      // NSUP*SEQ support rows
#define LSUP_PAD 4992  // 39*128, zero-padded K rows
#define QROWS 208      // padded qs rows per image (13*16)
#define BLOCK_W 980    // KS*SEQ rows per class block
#define OPT_STEPS 15
#define MTILES 39      // LSUP_PAD / MT
#define NSUPWG (NSUP * MTILES)   // 975 support GEMM blocks
#define NQWG   (NQRY * MTILES)   // 2925 query GEMM blocks

static constexpr float TEMP_F = 0.0510310363f;
static constexpr float INV_T  = 1.0f / TEMP_F;   // ~19.5959
static constexpr float LR_F   = 0.1f;

typedef short v8s __attribute__((ext_vector_type(8)));   // 8 x bf16 frag (4 VGPRs)
typedef float v4f __attribute__((ext_vector_type(4)));   // 4 x f32 acc

__device__ inline unsigned short f2bf(float x) {
    unsigned int u = __float_as_uint(x);
    u += 0x7fffu + ((u >> 16) & 1u);
    return (unsigned short)(u >> 16);
}

// fresh cross-XCD read: atomic RMW always executes at the coherence point
// (a relaxed/acquire atomic LOAD can be served from a stale local-XCD L2
// line until eviction — the round-2..5 ~5-10us/step exchange mystery).
__device__ __forceinline__ float fresh_f32(float* p) {
    return __hip_atomic_fetch_add(p, 0.0f, __ATOMIC_RELAXED, __HIP_MEMORY_SCOPE_AGENT);
}
__device__ __forceinline__ int fresh_i32(int* p) {
    return __hip_atomic_fetch_add(p, 0, __ATOMIC_RELAXED, __HIP_MEMORY_SCOPE_AGENT);
}
__device__ __forceinline__ unsigned fresh_u32(unsigned* p) {
    return __hip_atomic_fetch_add(p, 0u, __ATOMIC_RELAXED, __HIP_MEMORY_SCOPE_AGENT);
}

// ---------------------------------------------------------------------------
// Kernel 1: fused normalize. Wave-per-row.
// Rows [0, LSUP_PAD): K-side (pre-scaled 1/T, zero-padded tail).
// Rows [LSUP_PAD, LSUP_PAD + NIMG*QROWS): Q-side padded [100][208][384].
// ---------------------------------------------------------------------------
__global__ __launch_bounds__(256) void norm_all(const float* __restrict__ supk,
                                                const float* __restrict__ supq,
                                                const float* __restrict__ qry,
                                                unsigned short* __restrict__ Kb,
                                                unsigned short* __restrict__ Qall) {
    int R = blockIdx.x * 4 + (threadIdx.x >> 6);
    int l = threadIdx.x & 63;
    unsigned short* out;
    const float* in;
    float scale;
    if (R < LSUP_PAD) {
        out = Kb + (size_t)R * DIM;
        if (R >= LSUP) {
            #pragma unroll
            for (int k = 0; k < 6; ++k) out[l + 64 * k] = 0;
            return;
        }
        in = supk + (size_t)R * DIM;
        scale = INV_T;
    } else {
        int i = R - LSUP_PAD;
        int img = i / QROWS;
        int r = i - img * QROWS;
        out = Qall + (size_t)i * DIM;
        if (r >= SEQ) {
            #pragma unroll
            for (int k = 0; k < 6; ++k) out[l + 64 * k] = 0;
            return;
        }
        in = (img < NSUP)
            ? supq + ((size_t)img * SEQ + r) * DIM
            : qry  + ((size_t)(img - NSUP) * SEQ + r) * DIM;
        scale = 1.0f;
    }
    float x[6];
    #pragma unroll
    for (int k = 0; k < 6; ++k) x[k] = in[l + 64 * k];
    float s = 0.f;
    #pragma unroll
    for (int k = 0; k < 6; ++k) s += x[k] * x[k];
    #pragma unroll
    for (int m = 1; m < 64; m <<= 1) s += __shfl_xor(s, m);
    float sc = scale / fmaxf(sqrtf(s), 1e-8f);
    #pragma unroll
    for (int k = 0; k < 6; ++k) out[l + 64 * k] = f2bf(x[k] * sc);
}

// ---------------------------------------------------------------------------
// GEMM body: MFMA fused exp-sum, global_load_lds + XOR swizzle, XCD remap.
// 2M x 2N wave split. SUPPORT blocks write R via sc1 (agent) stores so the
// co-resident optimizer blocks can read them, then bump the done counter.
// ---------------------------------------------------------------------------
#define MT  128
#define NTP 208
#define KCC 64

__device__ __forceinline__ void gload16(const void* g, void* l) {
    __builtin_amdgcn_global_load_lds(
        (__attribute__((address_space(1))) void*)g,
        (__attribute__((address_space(3))) void*)l, 16, 0, 0);
}

template<int IMG_BASE, int NWG, bool SUPPORT>
__device__ __forceinline__ void gemm_body(
    int gid,
    const unsigned short* __restrict__ Kb,     // [4992][384] bf16, pre /T
    const unsigned short* __restrict__ Qall,   // [100][208][384] bf16
    float* __restrict__ Rall,
    unsigned* done,
    unsigned short* Asm, unsigned short* Bsm)
{
    int t = threadIdx.x;

    // bijective XCD-aware remap (m204)
    constexpr int qq = NWG >> 3;
    constexpr int rr = NWG & 7;
    int xcd = gid & 7;
    int sub = gid >> 3;
    int L = (xcd < rr ? xcd * (qq + 1) : rr * (qq + 1) + (xcd - rr) * qq) + sub;
    int img = IMG_BASE + L / MTILES;
    int m_base = (L % MTILES) * MT;

    const unsigned short* Qimg = Qall + (size_t)img * (QROWS * DIM);

    int wv = t >> 6;        // wave 0..3
    int l  = t & 63;
    int lo = l & 15;        // MFMA frag row/col index
    int hi = l >> 4;        // k-group
    int mh = (wv >> 1) * 64;   // M-half base row
    int nh = wv & 1;           // N-half

    int srow = l >> 3;
    int skp  = (l & 7) ^ srow;      // involution within 8-slot row
    const unsigned short* aSrc = Kb   + (size_t)(m_base + wv * 32 + srow) * DIM + skp * 8;
    const unsigned short* bSrc = Qimg + (size_t)srow * DIM + skp * 8;

    v4f acc[4][7];
    #pragma unroll
    for (int m = 0; m < 4; ++m)
        #pragma unroll
        for (int n = 0; n < 7; ++n)
            acc[m][n] = (v4f){0.f, 0.f, 0.f, 0.f};

    for (int kb = 0; kb < DIM; kb += KCC) {
        #pragma unroll
        for (int j = 0; j < 4; ++j)
            gload16(aSrc + (size_t)j * 8 * DIM + kb,
                    Asm + (wv * 32 + j * 8) * KCC);
        #pragma unroll
        for (int jj = 0; jj < 7; ++jj) {
            int j = wv + jj * 4;
            if (j < 26)
                gload16(bSrc + (size_t)j * 8 * DIM + kb,
                        Bsm + j * 8 * KCC);
        }
        __syncthreads();   // drains vmcnt before LDS reads

        const unsigned short* Ar = Asm + (mh + lo) * KCC;
        const unsigned short* Br = Bsm + (nh * 112 + lo) * KCC;
        #pragma unroll
        for (int kk = 0; kk < 2; ++kk) {
            int koff = ((hi + 4 * kk) ^ (lo & 7)) * 8;   // swizzled k-slot
            v8s a0 = *(const v8s*)(Ar + koff);
            v8s a1 = *(const v8s*)(Ar + 16 * KCC + koff);
            v8s a2 = *(const v8s*)(Ar + 32 * KCC + koff);
            v8s a3 = *(const v8s*)(Ar + 48 * KCC + koff);
            #pragma unroll
            for (int n = 0; n < 7; ++n) {
                if (nh == 0 || n < 6) {   // wave-uniform
                    v8s bb = *(const v8s*)(Br + n * 16 * KCC + koff);
                    acc[0][n] = __builtin_amdgcn_mfma_f32_16x16x32_bf16(a0, bb, acc[0][n], 0, 0, 0);
                    acc[1][n] = __builtin_amdgcn_mfma_f32_16x16x32_bf16(a1, bb, acc[1][n], 0, 0, 0);
                    acc[2][n] = __builtin_amdgcn_mfma_f32_16x16x32_bf16(a2, bb, acc[2][n], 0, 0, 0);
                    acc[3][n] = __builtin_amdgcn_mfma_f32_16x16x32_bf16(a3, bb, acc[3][n], 0, 0, 0);
                }
            }
        }
        __syncthreads();
    }

    // epilogue: exp + per-wave column-half sums. C/D: col=lo, row=hi*4+reg.
    float s[4][4];
    #pragma unroll
    for (int m = 0; m < 4; ++m)
        #pragma unroll
        for (int j = 0; j < 4; ++j) s[m][j] = 0.f;
    #pragma unroll
    for (int n = 0; n < 7; ++n) {
        if (nh == 0 || n < 6) {
            bool ok = ((nh * 7 + n) * 16 + lo) < SEQ;
            #pragma unroll
            for (int m = 0; m < 4; ++m)
                #pragma unroll
                for (int j = 0; j < 4; ++j)
                    s[m][j] += ok ? __expf(acc[m][n][j]) : 0.f;
        }
    }
    #pragma unroll
    for (int mm = 1; mm < 16; mm <<= 1) {
        #pragma unroll
        for (int m = 0; m < 4; ++m)
            #pragma unroll
            for (int j = 0; j < 4; ++j)
                s[m][j] += __shfl_xor(s[m][j], mm);
    }
    float* rp = (float*)Asm;   // reuse A LDS: [2][128] row partials
    if (lo == 0) {
        #pragma unroll
        for (int m = 0; m < 4; ++m)
            #pragma unroll
            for (int j = 0; j < 4; ++j)
                rp[nh * 128 + mh + m * 16 + hi * 4 + j] = s[m][j];
    }
    __syncthreads();
    if (t < MT) {
        int gr = m_base + t;
        if (gr < LSUP) {
            float o = rp[t] + rp[128 + t];
            if (img < NSUP && (gr / SEQ) == img) o = 0.f;
            if (SUPPORT)   // write-through to coherence point for opt blocks
                __hip_atomic_store(&Rall[(size_t)img * LSUP + gr], o,
                                   __ATOMIC_RELAXED, __HIP_MEMORY_SCOPE_AGENT);
            else
                Rall[(size_t)img * LSUP + gr] = o;
        }
    }
    if (SUPPORT) {
        __syncthreads();   // vmcnt(0): sc1 stores acked at coherence point
        if (t == 0)
            __hip_atomic_fetch_add(done, 1u, __ATOMIC_RELAXED, __HIP_MEMORY_SCOPE_AGENT);
    }
}

// ---------------------------------------------------------------------------
// Kernel 2: MEGA kernel. Blocks 0..4: optimizer (one class each).
// Blocks 5..979: support GEMM (sc1 R-writes + done counter).
// Blocks 980..3904: query GEMM.
// All cross-block READS in the optimizer are atomic RMWs (fetch_add 0) —
// guaranteed-fresh at the coherence point, immune to the stale-L2-line
// spin that made rounds 2-5's exchanges ~5-10us/step.
// ---------------------------------------------------------------------------
__global__ __launch_bounds__(256, 3) void mega(
    const unsigned short* __restrict__ Kb,
    const unsigned short* __restrict__ Qall,
    float* __restrict__ Rall,
    const int* __restrict__ labels,
    float* __restrict__ Dbufs,      // [16][125], pre-zeroed
    int* __restrict__ flags,        // [8], pre-zeroed; flags[w] = #pushD done
    unsigned* __restrict__ done,    // support-done counter, pre-zeroed
    float* __restrict__ e_out)      // [4900] final e^{v/T}
{
    __shared__ __align__(16) unsigned short Asm[MT * KCC];
    __shared__ __align__(16) unsigned short Bsm[NTP * KCC];

    if (blockIdx.x >= NW + NSUPWG) {
        gemm_body<NSUP, NQWG, false>((int)blockIdx.x - (NW + NSUPWG),
                                     Kb, Qall, Rall, done, Asm, Bsm);
        return;
    }
    if (blockIdx.x >= NW) {
        gemm_body<0, NSUPWG, true>((int)blockIdx.x - NW,
                                   Kb, Qall, Rall, done, Asm, Bsm);
        return;
    }

    // ---- optimizer block for class w ----
    float* sh  = (float*)Asm;
    float* red = sh;              // [4][25]
    float* cfs = sh + 100;        // [25]
    float* Dsm = sh + 128;        // [125]
    int*   lsm = (int*)(sh + 256);// [25]

    int w = blockIdx.x;
    int t = threadIdx.x;
    int wave = t >> 6, lane = t & 63;

    // wait for all 975 support blocks (RMW poll: always fresh)
    if (t == 0) {
        while (fresh_u32(done) < (unsigned)NSUPWG)
            __builtin_amdgcn_s_sleep(8);
    }
    __syncthreads();

    // rows r = t + 256k, k<4 (k=3 valid only for t<212); inactive rows -> 0.
    // Plain loads are safe: first touch of these lines in this kernel on
    // this XCD (kernel-entry invalidate kills prior-iteration copies), and
    // support blocks wrote them through to the coherence point.
    float Rv[4][NSUP];
    #pragma unroll
    for (int b = 0; b < NSUP; ++b) {
        const float* Rb = Rall + (size_t)b * LSUP + w * BLOCK_W;
        Rv[0][b] = Rb[t];
        Rv[1][b] = Rb[t + 256];
        Rv[2][b] = Rb[t + 512];
        Rv[3][b] = (t < BLOCK_W - 768) ? Rb[t + 768] : 0.f;
    }
    if (t < NSUP) lsm[t] = labels[t];

    float e0 = 1.f, e1 = 1.f, e2 = 1.f, e3 = 1.f;
    float v0 = 0.f, v1 = 0.f, v2 = 0.f, v3 = 0.f;

    auto pushD = [&](int step) {
        float part[NSUP];
        #pragma unroll
        for (int b = 0; b < NSUP; ++b)
            part[b] = e0 * Rv[0][b] + e1 * Rv[1][b] + e2 * Rv[2][b] + e3 * Rv[3][b];
        #pragma unroll
        for (int b = 0; b < NSUP; ++b) {
            #pragma unroll
            for (int m = 32; m; m >>= 1) part[b] += __shfl_xor(part[b], m);
        }
        if (lane == 0) {
            #pragma unroll
            for (int b = 0; b < NSUP; ++b) red[wave * NSUP + b] = part[b];
        }
        __syncthreads();
        if (t < NSUP) {
            float s = red[t] + red[NSUP + t] + red[2 * NSUP + t] + red[3 * NSUP + t];
            __hip_atomic_store(&Dbufs[step * 125 + t * 5 + w], s,
                               __ATOMIC_RELAXED, __HIP_MEMORY_SCOPE_AGENT);
        }
        __syncthreads();   // vmcnt(0) drain: payload acked at coherence point
        if (t == 0)
            __hip_atomic_store(&flags[w], step + 1,
                               __ATOMIC_RELAXED, __HIP_MEMORY_SCOPE_AGENT);
    };

    pushD(0);    // e = 1

    for (int s = 0; s < OPT_STEPS; ++s) {
        // wait for all 5 blocks' step-s D: polling wave, lanes 0..4, RMW
        if (wave == 0) {
            for (;;) {
                int f = (lane < NW) ? fresh_i32(&flags[lane]) : 0x7fffffff;
                if (__all(f >= s + 1)) break;
                __builtin_amdgcn_s_sleep(4);
            }
        }
        __syncthreads();
        if (t < 125)
            Dsm[t] = fresh_f32(&Dbufs[s * 125 + t]);
        __syncthreads();
        if (t < NSUP) {
            float Dsum = 0.f, Dw = 1.f;
            #pragma unroll
            for (int ww = 0; ww < NW; ++ww) {
                float d = Dsm[t * 5 + ww];
                Dsum += d;
                if (ww == w) Dw = d;
            }
            cfs[t] = ((Dw / Dsum) - (w == lsm[t] ? 1.f : 0.f)) * (INV_T / 25.f) / Dw;
        }
        __syncthreads();
        float g0 = 0.f, g1 = 0.f, g2 = 0.f, g3 = 0.f;
        #pragma unroll
        for (int b = 0; b < NSUP; ++b) {
            float c = cfs[b];
            g0 += c * Rv[0][b];
            g1 += c * Rv[1][b];
            g2 += c * Rv[2][b];
            g3 += c * Rv[3][b];
        }
        v0 -= LR_F * e0 * g0; e0 = __expf(v0 * INV_T);
        v1 -= LR_F * e1 * g1; e1 = __expf(v1 * INV_T);
        v2 -= LR_F * e2 * g2; e2 = __expf(v2 * INV_T);
        v3 -= LR_F * e3 * g3; e3 = __expf(v3 * INV_T);
        __syncthreads();      // red/Dsm/cfs reuse protection
        if (s + 1 < OPT_STEPS) pushD(s + 1);
    }

    // export e (plain stores; kernel-end writeback covers final_pred)
    float* eo = e_out + w * BLOCK_W;
    eo[t]       = e0;
    eo[t + 256] = e1;
    eo[t + 512] = e2;
    if (t < BLOCK_W - 768) eo[t + 768] = e3;
}

// ---------------------------------------------------------------------------
// Kernel 3: final prediction. 375 blocks (qb*5+w) x 256.
// ---------------------------------------------------------------------------
__global__ __launch_bounds__(256) void final_pred(const float* __restrict__ Rall,
                                                  const float* __restrict__ e_out,
                                                  float* __restrict__ out) {
    __shared__ float ws[4];
    int blk = blockIdx.x;
    int qb = blk / 5, w = blk % 5;
    const float* R  = Rall + (size_t)(NSUP + qb) * LSUP + w * BLOCK_W;
    const float* eb = e_out + w * BLOCK_W;
    int t = threadIdx.x;
    float p = 0.f;
    for (int i = t; i < BLOCK_W; i += 256) p += eb[i] * R[i];
    #pragma unroll
    for (int m = 32; m; m >>= 1) p += __shfl_xor(p, m);
    if ((t & 63) == 0) ws[t >> 6] = p;
    __syncthreads();
    if (t == 0) out[blk] = logf(ws[0] + ws[1] + ws[2] + ws[3]);
}

// ---------------------------------------------------------------------------
extern "C" void kernel_launch(void* const* d_in, const int* in_sizes, int n_in,
                              void* d_out, int out_size, void* d_ws, size_t ws_size,
                              hipStream_t stream) {
    const float* sup_key = (const float*)d_in[0];   // [25,196,384]
    const float* sup_qry = (const float*)d_in[1];   // [25,196,384]
    const float* qry     = (const float*)d_in[2];   // [75,196,384]
    const int*   labels  = (const int*)d_in[3];     // [25]
    float* out = (float*)d_out;                     // [75,5]

    char* ws = (char*)d_ws;
    size_t off = 0;
    auto take = [&](size_t bytes) {
        char* p = ws + off;
        off = (off + bytes + 255) & ~(size_t)255;
        return p;
    };
    unsigned short* Kb   = (unsigned short*)take((size_t)LSUP_PAD * DIM * 2);
    unsigned short* Qall = (unsigned short*)take((size_t)NIMG * QROWS * DIM * 2);
    float*          Rall = (float*)take((size_t)NIMG * LSUP * 4);
    float*          Dbuf = (float*)take(((size_t)(OPT_STEPS + 1) * 125 + 64) * 4);
    float*          eout = (float*)take((size_t)LSUP * 4);
    int*            flags = (int*)(Dbuf + (OPT_STEPS + 1) * 125);
    unsigned*       done  = (unsigned*)(flags + 8);

    hipMemsetAsync(Dbuf, 0, ((size_t)(OPT_STEPS + 1) * 125 + 64) * 4, stream);

    norm_all<<<(LSUP_PAD + NIMG * QROWS) / 4, 256, 0, stream>>>(
        sup_key, sup_qry, qry, Kb, Qall);

    mega<<<NW + NSUPWG + NQWG, 256, 0, stream>>>(
        Kb, Qall, Rall, labels, Dbuf, flags, done, eout);

    final_pred<<<NQRY * NW, 256, 0, stream>>>(Rall, eout, out);
}